// Round 9
// baseline (39.316 us; speedup 1.0000x reference)
//
#include <hip/hip_runtime.h>

// out[n,p] = sum_{k=0..7} X[n, p+k] * W[p*8 + k] + b[p],  X zero-padded past P.
// N=1024, P=20000, K=8, LF=1. fp32.
//
// Round-8 lesson: W access mode is fully off the critical path (LDS == L2 ==
// regs == 35-37us). The invariant across all flat rounds is the X-side VMEM
// structure: 3 overlapping loads/row/thread. Fix: one coalesced float4 load
// per lane; halo comes from lanes i+1, i+2 via __shfl_down. Wave produces 62
// output groups; lanes 62-63 are pure halo providers -> zero divergent patch
// loads. X L1 traffic 3x down (240->80MB/replay), VMEM instrs/row halved.

constexpr int N  = 1024;
constexpr int P  = 20000;
constexpr int K  = 8;
constexpr int P4 = P / 4;                        // 5000 float4 output groups
constexpr int GPW = 62;                          // useful groups per wave
constexpr int CWAVES = (P4 + GPW - 1) / GPW;     // 81 column-waves
constexpr int WPB = 4;                           // waves per 256-thr block
constexpr int CBLKS = (CWAVES + WPB - 1) / WPB;  // 21 column-blocks
constexpr int NCHUNKS = 128;                     // row-chunks
constexpr int ROWS = N / NCHUNKS;                // 8 rows per thread

typedef float float4n __attribute__((ext_vector_type(4)));

// ---- one-time W transpose: W[p][k] -> Wt[k][p] (640KB in d_ws) ----
__global__ __launch_bounds__(256)
void transpose_w(const float* __restrict__ W, float* __restrict__ Wt) {
    int p = blockIdx.x * blockDim.x + threadIdx.x;
    if (p >= P) return;
    float4 a = *reinterpret_cast<const float4*>(W + (size_t)p * K);
    float4 c = *reinterpret_cast<const float4*>(W + (size_t)p * K + 4);
    Wt[0 * P + p] = a.x; Wt[1 * P + p] = a.y;
    Wt[2 * P + p] = a.z; Wt[3 * P + p] = a.w;
    Wt[4 * P + p] = c.x; Wt[5 * P + p] = c.y;
    Wt[6 * P + p] = c.z; Wt[7 * P + p] = c.w;
}

__device__ __forceinline__ float4n shdn(float4n v, int d) {
    float4n r;
    r.x = __shfl_down(v.x, d);
    r.y = __shfl_down(v.y, d);
    r.z = __shfl_down(v.z, d);
    r.w = __shfl_down(v.w, d);
    return r;
}

__global__ __launch_bounds__(256, 4)
void local_linear_kernel(const float* __restrict__ X,
                         const float* __restrict__ Wt,
                         const float* __restrict__ b,
                         float* __restrict__ out) {
    const int chunk = blockIdx.x / CBLKS;
    const int cblk  = blockIdx.x - chunk * CBLKS;
    const int wid   = threadIdx.x >> 6;
    const int lane  = threadIdx.x & 63;
    const int cw    = cblk * WPB + wid;           // column-wave index
    const int q0    = cw * GPW;
    if (q0 >= P4) return;                         // wave-uniform early-out
    const int q     = q0 + lane;                  // my float4 group
    const int p     = q * 4;
    const int psafe = (p <= P - 4) ? p : (P - 4); // clamp for halo lanes
    const int n0    = chunk * ROWS;
    const bool interior = (p + 12 <= P);          // can use shuffle halo
    const bool doStore  = (lane < GPW) && (q < P4);

    // W for my 4 columns: 8 coalesced float4 loads (lanes contiguous)
    float4n wv[8];
    #pragma unroll
    for (int k = 0; k < K; ++k)
        wv[k] = *reinterpret_cast<const float4n*>(Wt + (size_t)k * P + psafe);
    float4n bv = *reinterpret_cast<const float4n*>(b + psafe);
    asm volatile("" : "+v"(wv[0]), "+v"(wv[1]), "+v"(wv[2]), "+v"(wv[3]),
                      "+v"(wv[4]), "+v"(wv[5]), "+v"(wv[6]), "+v"(wv[7]),
                      "+v"(bv));

    #pragma unroll 4
    for (int r = 0; r < ROWS; ++r) {
        const float* xrow = X + (size_t)(n0 + r) * P;

        // ONE coalesced load per lane; halo via cross-lane shuffles.
        // Shuffles run with all 64 lanes active (no divergence above).
        float4n x0 = *reinterpret_cast<const float4n*>(xrow + psafe);
        float4n x1 = shdn(x0, 1);                 // lanes i+1's X[p+4..p+7]
        float4n x2 = shdn(x0, 2);                 // lanes i+2's X[p+8..p+11]

        float xv[12];
        if (interior) {
            xv[0] = x0.x; xv[1] = x0.y; xv[2]  = x0.z; xv[3]  = x0.w;
            xv[4] = x1.x; xv[5] = x1.y; xv[6]  = x1.z; xv[7]  = x1.w;
            xv[8] = x2.x; xv[9] = x2.y; xv[10] = x2.z; xv[11] = x2.w;
        } else {
            // Tail lanes (q=4998,4999) + garbage lanes (q>=5000, no loads).
            #pragma unroll
            for (int i = 0; i < 12; ++i)
                xv[i] = (p + i < P) ? xrow[p + i] : 0.0f;  // matches jnp.pad
        }

        float r0 = bv.x, r1 = bv.y, r2 = bv.z, r3 = bv.w;
        #pragma unroll
        for (int k = 0; k < K; ++k) {
            r0 += xv[k + 0] * wv[k].x;
            r1 += xv[k + 1] * wv[k].y;
            r2 += xv[k + 2] * wv[k].z;
            r3 += xv[k + 3] * wv[k].w;
        }

        if (doStore) {
            float4n o; o.x = r0; o.y = r1; o.z = r2; o.w = r3;
            __builtin_nontemporal_store(
                o, reinterpret_cast<float4n*>(out + (size_t)(n0 + r) * P + p));
        }
    }
}

extern "C" void kernel_launch(void* const* d_in, const int* in_sizes, int n_in,
                              void* d_out, int out_size, void* d_ws, size_t ws_size,
                              hipStream_t stream) {
    const float* X = (const float*)d_in[0];
    const float* W = (const float*)d_in[1];
    const float* b = (const float*)d_in[2];
    float* out = (float*)d_out;

    constexpr int block = 256;
    constexpr int grid = CBLKS * NCHUNKS;          // 2,688 blocks (10,752 waves)

    float* Wt = (float*)d_ws;                      // 640KB scratch
    transpose_w<<<(P + block - 1) / block, block, 0, stream>>>(W, Wt);
    local_linear_kernel<<<grid, block, 0, stream>>>(X, Wt, b, out);
}

// Round 10
// 38.206 us; speedup vs baseline: 1.0290x; 1.0290x over previous
//
#include <hip/hip_runtime.h>

// out[n,p] = sum_{k=0..7} X[n, p+k] * W[p*8 + k] + b[p],  X zero-padded past P.
// N=1024, P=20000, K=8, LF=1. fp32.
//
// Round-9 lesson: VMEM instr count / W path / L3 pollution all refuted (main
// kernel pinned at ~35us since R2). VALUBusy=10% -> SIMDs stall on vmcnt 90%
// of time; occupancy ~52% is GRID-shaped (10240 waves = 1.25 rounds of the
// 8192-wave capacity), not resource-capped. Fix: ROWS=2, NCHUNKS=512 ->
// 40960 waves = exactly 5.0 full occupancy rounds, ~95%+ average residency,
// 2x the resident loads in flight.

constexpr int N  = 1024;
constexpr int P  = 20000;
constexpr int K  = 8;
constexpr int P4 = P / 4;              // 5000 float4 output groups
constexpr int CPB = 20;                // column-blocks per chunk (5120/256)
constexpr int NCHUNKS = 512;           // row-chunks
constexpr int ROWS = N / NCHUNKS;      // 2 rows per thread

typedef float float4n __attribute__((ext_vector_type(4)));

// ---- one-time W transpose: W[p][k] -> Wt[k][p] (640KB in d_ws) ----
__global__ __launch_bounds__(256)
void transpose_w(const float* __restrict__ W, float* __restrict__ Wt) {
    int p = blockIdx.x * blockDim.x + threadIdx.x;
    if (p >= P) return;
    float4 a = *reinterpret_cast<const float4*>(W + (size_t)p * K);
    float4 c = *reinterpret_cast<const float4*>(W + (size_t)p * K + 4);
    Wt[0 * P + p] = a.x; Wt[1 * P + p] = a.y;
    Wt[2 * P + p] = a.z; Wt[3 * P + p] = a.w;
    Wt[4 * P + p] = c.x; Wt[5 * P + p] = c.y;
    Wt[6 * P + p] = c.z; Wt[7 * P + p] = c.w;
}

__global__ __launch_bounds__(256)
void local_linear_kernel(const float* __restrict__ X,
                         const float* __restrict__ Wt,
                         const float* __restrict__ b,
                         float* __restrict__ out) {
    const int bid   = blockIdx.x;
    const int chunk = bid / CPB;
    const int cblk  = bid - chunk * CPB;
    const int q     = cblk * 256 + threadIdx.x;   // float4 output group
    if (q >= P4) return;                          // only in last cblk
    const int p  = q * 4;
    const int n0 = chunk * ROWS;

    // W for my 4 columns: 8 coalesced float4 loads (lanes have consecutive p)
    float4n wv[8];
    #pragma unroll
    for (int k = 0; k < K; ++k)
        wv[k] = *reinterpret_cast<const float4n*>(Wt + (size_t)k * P + p);
    const float4n bv = *reinterpret_cast<const float4n*>(b + p);

    const bool interior = (p + 12 <= P);

    #pragma unroll
    for (int r = 0; r < ROWS; ++r) {
        const float* xrow = X + (size_t)(n0 + r) * P;

        float xv[12];
        if (interior) {
            float4n a = *reinterpret_cast<const float4n*>(xrow + p);
            float4n c = *reinterpret_cast<const float4n*>(xrow + p + 4);
            float4n d = *reinterpret_cast<const float4n*>(xrow + p + 8);
            xv[0] = a.x; xv[1] = a.y; xv[2]  = a.z; xv[3]  = a.w;
            xv[4] = c.x; xv[5] = c.y; xv[6]  = c.z; xv[7]  = c.w;
            xv[8] = d.x; xv[9] = d.y; xv[10] = d.z; xv[11] = d.w;
        } else {
            #pragma unroll
            for (int i = 0; i < 12; ++i)
                xv[i] = (p + i < P) ? xrow[p + i] : 0.0f;   // matches jnp.pad
        }

        float r0 = bv.x, r1 = bv.y, r2 = bv.z, r3 = bv.w;
        #pragma unroll
        for (int k = 0; k < K; ++k) {
            r0 += xv[k + 0] * wv[k].x;
            r1 += xv[k + 1] * wv[k].y;
            r2 += xv[k + 2] * wv[k].z;
            r3 += xv[k + 3] * wv[k].w;
        }

        float4n o; o.x = r0; o.y = r1; o.z = r2; o.w = r3;
        __builtin_nontemporal_store(
            o, reinterpret_cast<float4n*>(out + (size_t)(n0 + r) * P + p));
    }
}

extern "C" void kernel_launch(void* const* d_in, const int* in_sizes, int n_in,
                              void* d_out, int out_size, void* d_ws, size_t ws_size,
                              hipStream_t stream) {
    const float* X = (const float*)d_in[0];
    const float* W = (const float*)d_in[1];
    const float* b = (const float*)d_in[2];
    float* out = (float*)d_out;

    constexpr int block = 256;
    constexpr int grid = CPB * NCHUNKS;            // 10,240 blocks = 40,960 waves
                                                   // = exactly 5 occupancy rounds

    float* Wt = (float*)d_ws;                      // 640KB scratch
    transpose_w<<<(P + block - 1) / block, block, 0, stream>>>(W, Wt);
    local_linear_kernel<<<grid, block, 0, stream>>>(X, Wt, b, out);
}